// Round 1
// baseline (2564.461 us; speedup 1.0000x reference)
//
#include <hip/hip_runtime.h>

// ModalVerlet: B=16 batches, M=64 modes, T=48000 samples.
// Modes are independent (elementwise recurrence); only w = sum_m(Phi_o*q) couples
// modes, and it does not feed back. Kernel 1: one lane per (b,m), serial scan in
// registers, 1 tanh/step (corrector tanh reused as next predictor tanh), outputs
// buffered 4 steps -> aligned dwordx4 stores (per-lane y rows are t-contiguous).
// Kernel 2: w as a parallel memory-bound reduction over the stored q rows.

#define NB 16
#define NM 64
#define NT 48000
#define NCHUNK (NT / 4) // 12000

__device__ __forceinline__ float tanh_fast(float x) {
    // tanh(x) = 1 - 2/(exp2(2*log2(e)*x) + 1)
    // 5-op dependent chain, branchless, exact at +-inf (exp2 overflow -> 1-0).
    float y = __builtin_amdgcn_exp2f(x * 2.88539008177792681472f);
    return fmaf(-2.0f, __builtin_amdgcn_rcpf(y + 1.0f), 1.0f);
}

__global__ void __launch_bounds__(NM, 1) modal_scan_kernel(
    const float* __restrict__ y0,
    const float* __restrict__ omega,
    const float* __restrict__ sigma,
    const float* __restrict__ gamma,
    const float* __restrict__ Phi_e,
    const float* __restrict__ fe_points,
    float* __restrict__ y_out)
{
    const int b = blockIdx.x;
    const int m = threadIdx.x;

    const float om  = omega[b * NM + m];
    const float sg  = sigma[b * NM + m];
    const float g   = gamma[b];
    const float om2 = om * om;
    const float g2  = g * g;
    const float two_sig = 2.0f * sg;
    const float phe = Phi_e[b * NM + m];

    const float k   = 1.0f / 48000.0f;
    const float k2  = 0.5f * k;
    const float inv_d = 1.0f / (1.0f + k * sg);
    const float k2d = k2 * inv_d;

    float q = y0[b * 2 * NM + m];
    float p = y0[b * 2 * NM + NM + m];

    const float*  fe  = fe_points + (size_t)b * NT;
    const float4* fe4 = reinterpret_cast<const float4*>(fe);
    float* yq = y_out + ((size_t)b * 2 * NM + m) * NT;
    float* yp = yq + (size_t)NM * NT;

    // carry: (q, p, corr) where corr = -om2*q + g2*tanh(q) + fe[t]*phe
    float4 f4 = fe4[0];
    float t0   = tanh_fast(q);
    float corr = fmaf(-om2, q, fmaf(g2, t0, f4.x * phe));

    float vq0 = q, vq1, vq2, vq3;
    float vp0 = p, vp1, vp2, vp3;

    // One step producing state index tt; FE = fe[tt].
    // pd' reuses corr from previous step's corrector (exact reuse: fe0_{t+1}=fe1_t,
    // tanh(q_{t+1}) computed here as t1).
#define STEP(FE) {                                    \
    float pd = fmaf(-two_sig, p, corr);               \
    float ph = fmaf(k2, pd, p);                       \
    float q1 = fmaf(k, ph, q);                        \
    float t1 = tanh_fast(q1);                         \
    float G1 = fmaf(g2, t1, (FE) * phe);              \
    float c1 = fmaf(-om2, q1, G1);                    \
    float p1 = fmaf(k2d, c1, inv_d * ph);             \
    q = q1; p = p1; corr = c1; }

    // chunk 0: state 0 = initial condition, then states 1..3
    STEP(f4.y); vq1 = q; vp1 = p;
    STEP(f4.z); vq2 = q; vp2 = p;
    STEP(f4.w); vq3 = q; vp3 = p;
    *reinterpret_cast<float4*>(yq) = make_float4(vq0, vq1, vq2, vq3);
    *reinterpret_cast<float4*>(yp) = make_float4(vp0, vp1, vp2, vp3);

    float4 fnext = fe4[1];
    for (int c = 1; c < NCHUNK; ++c) {
        float4 fc = fnext;
        int cn = (c + 1 < NCHUNK) ? (c + 1) : (NCHUNK - 1);
        fnext = fe4[cn]; // prefetch next chunk's forcing (uniform -> s_load)

        STEP(fc.x); vq0 = q; vp0 = p;
        STEP(fc.y); vq1 = q; vp1 = p;
        STEP(fc.z); vq2 = q; vp2 = p;
        STEP(fc.w); vq3 = q; vp3 = p;

        *reinterpret_cast<float4*>(yq + 4 * c) = make_float4(vq0, vq1, vq2, vq3);
        *reinterpret_cast<float4*>(yp + 4 * c) = make_float4(vp0, vp1, vp2, vp3);
    }
#undef STEP
}

// w[b,t] = sum_m Phi_o[b,m] * y[b,m,t]  (fully parallel, memory-bound)
__global__ void __launch_bounds__(256) w_kernel(
    const float* __restrict__ y,
    const float* __restrict__ Phi_o,
    float* __restrict__ w)
{
    const int b  = blockIdx.y;
    const int t4 = blockIdx.x * 256 + threadIdx.x;
    if (t4 >= NT / 4) return;

    const float4* yb = reinterpret_cast<const float4*>(y + (size_t)b * 2 * NM * NT);
    const float*  po = Phi_o + b * NM;

    float4 acc = make_float4(0.f, 0.f, 0.f, 0.f);
    #pragma unroll 8
    for (int mm = 0; mm < NM; ++mm) {
        float  c = po[mm];
        float4 v = yb[mm * (NT / 4) + t4];
        acc.x = fmaf(c, v.x, acc.x);
        acc.y = fmaf(c, v.y, acc.y);
        acc.z = fmaf(c, v.z, acc.z);
        acc.w = fmaf(c, v.w, acc.w);
    }
    reinterpret_cast<float4*>(w + (size_t)b * NT)[t4] = acc;
}

extern "C" void kernel_launch(void* const* d_in, const int* in_sizes, int n_in,
                              void* d_out, int out_size, void* d_ws, size_t ws_size,
                              hipStream_t stream)
{
    // inputs: 0=fs, 1=num_samples, 2=y0, 3=omega, 4=sigma, 5=gamma,
    //         6=Phi_e, 7=Phi_o, 8=fe_points
    const float* y0      = (const float*)d_in[2];
    const float* omega   = (const float*)d_in[3];
    const float* sigma   = (const float*)d_in[4];
    const float* gamma   = (const float*)d_in[5];
    const float* Phi_e   = (const float*)d_in[6];
    const float* Phi_o   = (const float*)d_in[7];
    const float* fe      = (const float*)d_in[8];

    float* y_out = (float*)d_out;                       // (B, 2M, T)
    float* w_out = y_out + (size_t)NB * 2 * NM * NT;    // (B, T)

    modal_scan_kernel<<<NB, NM, 0, stream>>>(y0, omega, sigma, gamma, Phi_e, fe, y_out);

    dim3 grid((NT / 4 + 255) / 256, NB);
    w_kernel<<<grid, 256, 0, stream>>>(y_out, Phi_o, w_out);
}

// Round 2
// 1990.445 us; speedup vs baseline: 1.2884x; 1.2884x over previous
//
#include <hip/hip_runtime.h>

// ModalVerlet: B=16, M=64, T=48000. One lane per (b,m); serial scan in registers.
// Chain-minimized recurrence: carry c_t = -om2*q_t + g2*tanh(q_t) + fe_t*phe and
// use the lagged expansion q_s = q_{s-1} + AF*p_{s-2} + AG*c_{s-2} + AGB*c_{s-1},
// with tanh folded as 1-2*rcp(exp2(C*q)+1). Critical chain per step:
//   fma(q) -> mul -> exp2 -> add -> rcp        (5 dependent ops)
// All other work (V, cb, p, w) has one-step slack. 16 steps/iter in distinct SSA
// registers so store-retirement (vmcnt) never stalls the chain (the round-1
// kernel at VGPR=12 recycled store registers every 4 steps -> ~350 cyc/iter stall).

#define NB 16
#define NM 64
#define NT 48000
#define SPI 16
#define NITER (NT / SPI) // 3000

__global__ void __launch_bounds__(NM, 1) modal_scan_kernel(
    const float* __restrict__ y0,
    const float* __restrict__ omega,
    const float* __restrict__ sigma,
    const float* __restrict__ gamma,
    const float* __restrict__ Phi_e,
    const float* __restrict__ fe_points,
    float* __restrict__ y_out)
{
    const int b = blockIdx.x;
    const int m = threadIdx.x;

    const float om  = omega[b * NM + m];
    const float sg  = sigma[b * NM + m];
    const float g   = gamma[b];
    const float phe = Phi_e[b * NM + m];
    const float om2 = om * om;
    const float g2  = g * g;

    const float k    = 1.0f / 48000.0f;
    const float k2   = 0.5f * k;
    const float E    = 1.0f - k * sg;            // 1 - k*sigma
    const float dinv = 1.0f / (1.0f + k * sg);
    const float A    = k * E;
    const float Bc   = k * k2;                   // k^2/2
    const float Fd   = E * dinv;
    const float Gd   = k2 * dinv;
    const float AF   = A * Fd;
    const float AG   = A * Gd;
    const float AGB  = AG + Bc;
    const float m2g2 = -2.0f * g2;
    const float AGBm2g2 = AGB * m2g2;
    const float Ct   = 2.885390081777927f;       // 2*log2(e)

    const float q0v = y0[b * 2 * NM + m];
    const float p0v = y0[b * 2 * NM + NM + m];

    const float*  fe  = fe_points + (size_t)b * NT;
    const float4* fe4 = reinterpret_cast<const float4*>(fe);
    float* yq = y_out + ((size_t)b * 2 * NM + m) * (size_t)NT;
    float* yp = yq + (size_t)NM * NT;

#define RCH(x) __builtin_amdgcn_rcpf(__builtin_amdgcn_exp2f((x) * Ct) + 1.0f)

    // ---- preamble: states 0 and 1 (direct form) ----
    float4 f0 = fe4[0], f1 = fe4[1], f2 = fe4[2], f3 = fe4[3];

    float r0   = RCH(q0v);
    float cb0  = fmaf(-om2, q0v, fmaf(phe, f0.x, g2));
    float c0   = fmaf(m2g2, r0, cb0);
    float q1v  = fmaf(Bc, c0, fmaf(A, p0v, q0v));
    float rP   = RCH(q1v);
    float cbP  = fmaf(-om2, q1v, fmaf(phe, f0.y, g2));
    float wPm1 = fmaf(Fd, p0v, Gd * c0);
    float q1   = q1v;
    float pPm2 = p0v;
    float cPm2 = c0;

    // STEP producing state s: finalizes c_{s-1}, p_{s-1}; q_s on the 5-op chain.
#define STEP(FE, QV, PST) {                                          \
    float cP  = fmaf(m2g2, rP, cbP);            /* c_{s-1}        */ \
    float pP  = fmaf(Gd, cP, wPm1);             /* p_{s-1}        */ \
    float V   = fmaf(AGB, cbP, fmaf(AG, cPm2, fmaf(AF, pPm2, q1))); \
    float qn  = fmaf(AGBm2g2, rP, V);           /* q_s  [CHAIN]   */ \
    float rn  = RCH(qn);                        /*      [CHAIN]   */ \
    float cbn = fmaf(-om2, qn, fmaf(phe, (FE), g2));                 \
    float wn  = fmaf(Fd, pP, Gd * cP);                               \
    PST;                                                             \
    QV = qn;                                                         \
    q1 = qn; rP = rn; cbP = cbn; pPm2 = pP; cPm2 = cP; wPm1 = wn; }

    // ---- iteration 0: states 0..15 ----
    {
        float vq2, vq3, vq4, vq5, vq6, vq7, vq8, vq9, vq10, vq11, vq12, vq13, vq14, vq15;
        __builtin_nontemporal_store(p0v, yp + 0);
        STEP(f0.z, vq2,  __builtin_nontemporal_store(pP, yp + 1));
        STEP(f0.w, vq3,  __builtin_nontemporal_store(pP, yp + 2));
        STEP(f1.x, vq4,  __builtin_nontemporal_store(pP, yp + 3));
        STEP(f1.y, vq5,  __builtin_nontemporal_store(pP, yp + 4));
        STEP(f1.z, vq6,  __builtin_nontemporal_store(pP, yp + 5));
        STEP(f1.w, vq7,  __builtin_nontemporal_store(pP, yp + 6));
        STEP(f2.x, vq8,  __builtin_nontemporal_store(pP, yp + 7));
        STEP(f2.y, vq9,  __builtin_nontemporal_store(pP, yp + 8));
        STEP(f2.z, vq10, __builtin_nontemporal_store(pP, yp + 9));
        STEP(f2.w, vq11, __builtin_nontemporal_store(pP, yp + 10));
        STEP(f3.x, vq12, __builtin_nontemporal_store(pP, yp + 11));
        STEP(f3.y, vq13, __builtin_nontemporal_store(pP, yp + 12));
        STEP(f3.z, vq14, __builtin_nontemporal_store(pP, yp + 13));
        STEP(f3.w, vq15, __builtin_nontemporal_store(pP, yp + 14));
        *reinterpret_cast<float4*>(yq + 0)  = make_float4(q0v, q1v, vq2, vq3);
        *reinterpret_cast<float4*>(yq + 4)  = make_float4(vq4, vq5, vq6, vq7);
        *reinterpret_cast<float4*>(yq + 8)  = make_float4(vq8, vq9, vq10, vq11);
        *reinterpret_cast<float4*>(yq + 12) = make_float4(vq12, vq13, vq14, vq15);
    }

    // ---- main loop: iter j covers states 16j..16j+15 ----
    float4 fn0 = fe4[4], fn1 = fe4[5], fn2 = fe4[6], fn3 = fe4[7];
    for (int j = 1; j < NITER; ++j) {
        const float4 fc0 = fn0, fc1 = fn1, fc2 = fn2, fc3 = fn3;
        const int jn = (j + 1 < NITER) ? (j + 1) : (NITER - 1);
        fn0 = fe4[4 * jn + 0]; fn1 = fe4[4 * jn + 1];
        fn2 = fe4[4 * jn + 2]; fn3 = fe4[4 * jn + 3];

        float* yqj = yq + 16 * (size_t)j;
        float* ypj = yp + 16 * (size_t)j;
        float vq0, vq1, vq2, vq3, vq4, vq5, vq6, vq7;
        float vq8, vq9, vq10, vq11, vq12, vq13, vq14, vq15;

        STEP(fc0.x, vq0,  __builtin_nontemporal_store(pP, ypj - 1));
        STEP(fc0.y, vq1,  __builtin_nontemporal_store(pP, ypj + 0));
        STEP(fc0.z, vq2,  __builtin_nontemporal_store(pP, ypj + 1));
        STEP(fc0.w, vq3,  __builtin_nontemporal_store(pP, ypj + 2));
        STEP(fc1.x, vq4,  __builtin_nontemporal_store(pP, ypj + 3));
        STEP(fc1.y, vq5,  __builtin_nontemporal_store(pP, ypj + 4));
        STEP(fc1.z, vq6,  __builtin_nontemporal_store(pP, ypj + 5));
        STEP(fc1.w, vq7,  __builtin_nontemporal_store(pP, ypj + 6));
        STEP(fc2.x, vq8,  __builtin_nontemporal_store(pP, ypj + 7));
        STEP(fc2.y, vq9,  __builtin_nontemporal_store(pP, ypj + 8));
        STEP(fc2.z, vq10, __builtin_nontemporal_store(pP, ypj + 9));
        STEP(fc2.w, vq11, __builtin_nontemporal_store(pP, ypj + 10));
        STEP(fc3.x, vq12, __builtin_nontemporal_store(pP, ypj + 11));
        STEP(fc3.y, vq13, __builtin_nontemporal_store(pP, ypj + 12));
        STEP(fc3.z, vq14, __builtin_nontemporal_store(pP, ypj + 13));
        STEP(fc3.w, vq15, __builtin_nontemporal_store(pP, ypj + 14));

        *reinterpret_cast<float4*>(yqj + 0)  = make_float4(vq0, vq1, vq2, vq3);
        *reinterpret_cast<float4*>(yqj + 4)  = make_float4(vq4, vq5, vq6, vq7);
        *reinterpret_cast<float4*>(yqj + 8)  = make_float4(vq8, vq9, vq10, vq11);
        *reinterpret_cast<float4*>(yqj + 12) = make_float4(vq12, vq13, vq14, vq15);
    }

    // ---- epilogue: p at the final state ----
    float cPf = fmaf(m2g2, rP, cbP);
    float pPf = fmaf(Gd, cPf, wPm1);
    __builtin_nontemporal_store(pPf, yp + (NT - 1));
#undef STEP
#undef RCH
}

// w[b,t] = sum_m Phi_o[b,m] * y[b,m,t]  (fully parallel, memory/L3-bound)
__global__ void __launch_bounds__(256) w_kernel(
    const float* __restrict__ y,
    const float* __restrict__ Phi_o,
    float* __restrict__ w)
{
    const int b  = blockIdx.y;
    const int t4 = blockIdx.x * 256 + threadIdx.x;
    if (t4 >= NT / 4) return;

    const float4* yb = reinterpret_cast<const float4*>(y + (size_t)b * 2 * NM * NT);
    const float*  po = Phi_o + b * NM;

    float4 acc = make_float4(0.f, 0.f, 0.f, 0.f);
    #pragma unroll 8
    for (int mm = 0; mm < NM; ++mm) {
        float  c = po[mm];
        float4 v = yb[mm * (NT / 4) + t4];
        acc.x = fmaf(c, v.x, acc.x);
        acc.y = fmaf(c, v.y, acc.y);
        acc.z = fmaf(c, v.z, acc.z);
        acc.w = fmaf(c, v.w, acc.w);
    }
    reinterpret_cast<float4*>(w + (size_t)b * NT)[t4] = acc;
}

extern "C" void kernel_launch(void* const* d_in, const int* in_sizes, int n_in,
                              void* d_out, int out_size, void* d_ws, size_t ws_size,
                              hipStream_t stream)
{
    // inputs: 0=fs, 1=num_samples, 2=y0, 3=omega, 4=sigma, 5=gamma,
    //         6=Phi_e, 7=Phi_o, 8=fe_points
    const float* y0    = (const float*)d_in[2];
    const float* omega = (const float*)d_in[3];
    const float* sigma = (const float*)d_in[4];
    const float* gamma = (const float*)d_in[5];
    const float* Phi_e = (const float*)d_in[6];
    const float* Phi_o = (const float*)d_in[7];
    const float* fe    = (const float*)d_in[8];

    float* y_out = (float*)d_out;                    // (B, 2M, T)
    float* w_out = y_out + (size_t)NB * 2 * NM * NT; // (B, T)

    modal_scan_kernel<<<NB, NM, 0, stream>>>(y0, omega, sigma, gamma, Phi_e, fe, y_out);

    dim3 grid((NT / 4 + 255) / 256, NB);
    w_kernel<<<grid, 256, 0, stream>>>(y_out, Phi_o, w_out);
}